// Round 1
// baseline (398.332 us; speedup 1.0000x reference)
//
#include <hip/hip_runtime.h>

#define HH 768
#define SS 512
#define NB 2
#define NHEADS 12
#define KTOP 256
#define ETOT (NB*SS*KTOP)        // 262144
#define LN_EPS 1e-5f

// Output layout (floats): node_features [786432] | edge_index [524288] | edge_attr [201326592]
#define EI_OFF 786432L
#define EA_OFF 1310720L

// ---------------------------------------------------------------------------
// C[M,N] = scale * (A[M,K] @ W[N,K]^T) + bias ; strided batch via blockIdx.z
// Tiles: 64x64, BK=32, 256 threads, 4x4 acc per thread.
// ---------------------------------------------------------------------------
__global__ __launch_bounds__(256) void gemm_at(
    const float* __restrict__ A, const float* __restrict__ W,
    const float* __restrict__ bias, float* __restrict__ C,
    int K, int lda, int ldw, int ldc,
    long aOffB, long aOffH, long wOffB, long wOffH, long cOffZ, float scale)
{
    const int z  = blockIdx.z;
    const int bz = z / NHEADS, hz = z - bz * NHEADS;
    A += (long)bz * aOffB + (long)hz * aOffH;
    W += (long)bz * wOffB + (long)hz * wOffH;
    C += (long)z * cOffZ;

    __shared__ float As[32][68];
    __shared__ float Ws[32][68];

    const int tid = threadIdx.x;
    const int tm  = tid >> 4;          // 0..15
    const int tn  = tid & 15;          // 0..15
    const int m0  = blockIdx.y * 64;
    const int n0  = blockIdx.x * 64;

    const int srow = tid >> 3;         // 0..31
    const int sc4  = tid & 7;          // 0..7

    float acc[4][4] = {};

    for (int kt = 0; kt < K; kt += 32) {
        const float4 av0 = *(const float4*)(A + (long)(m0 + srow)      * lda + kt + sc4 * 4);
        const float4 av1 = *(const float4*)(A + (long)(m0 + srow + 32) * lda + kt + sc4 * 4);
        const float4 wv0 = *(const float4*)(W + (long)(n0 + srow)      * ldw + kt + sc4 * 4);
        const float4 wv1 = *(const float4*)(W + (long)(n0 + srow + 32) * ldw + kt + sc4 * 4);
        __syncthreads();
        As[sc4*4+0][srow]    = av0.x; As[sc4*4+1][srow]    = av0.y;
        As[sc4*4+2][srow]    = av0.z; As[sc4*4+3][srow]    = av0.w;
        As[sc4*4+0][srow+32] = av1.x; As[sc4*4+1][srow+32] = av1.y;
        As[sc4*4+2][srow+32] = av1.z; As[sc4*4+3][srow+32] = av1.w;
        Ws[sc4*4+0][srow]    = wv0.x; Ws[sc4*4+1][srow]    = wv0.y;
        Ws[sc4*4+2][srow]    = wv0.z; Ws[sc4*4+3][srow]    = wv0.w;
        Ws[sc4*4+0][srow+32] = wv1.x; Ws[sc4*4+1][srow+32] = wv1.y;
        Ws[sc4*4+2][srow+32] = wv1.z; Ws[sc4*4+3][srow+32] = wv1.w;
        __syncthreads();
        #pragma unroll
        for (int k = 0; k < 32; ++k) {
            const float4 a = *(const float4*)&As[k][tm*4];
            const float4 b = *(const float4*)&Ws[k][tn*4];
            acc[0][0] = fmaf(a.x, b.x, acc[0][0]);
            acc[0][1] = fmaf(a.x, b.y, acc[0][1]);
            acc[0][2] = fmaf(a.x, b.z, acc[0][2]);
            acc[0][3] = fmaf(a.x, b.w, acc[0][3]);
            acc[1][0] = fmaf(a.y, b.x, acc[1][0]);
            acc[1][1] = fmaf(a.y, b.y, acc[1][1]);
            acc[1][2] = fmaf(a.y, b.z, acc[1][2]);
            acc[1][3] = fmaf(a.y, b.w, acc[1][3]);
            acc[2][0] = fmaf(a.z, b.x, acc[2][0]);
            acc[2][1] = fmaf(a.z, b.y, acc[2][1]);
            acc[2][2] = fmaf(a.z, b.z, acc[2][2]);
            acc[2][3] = fmaf(a.z, b.w, acc[2][3]);
            acc[3][0] = fmaf(a.w, b.x, acc[3][0]);
            acc[3][1] = fmaf(a.w, b.y, acc[3][1]);
            acc[3][2] = fmaf(a.w, b.z, acc[3][2]);
            acc[3][3] = fmaf(a.w, b.w, acc[3][3]);
        }
    }

    float4 bv = make_float4(0.f, 0.f, 0.f, 0.f);
    if (bias) bv = *(const float4*)(bias + n0 + tn * 4);
    #pragma unroll
    for (int i = 0; i < 4; ++i) {
        float4 r;
        r.x = fmaf(acc[i][0], scale, bv.x);
        r.y = fmaf(acc[i][1], scale, bv.y);
        r.z = fmaf(acc[i][2], scale, bv.z);
        r.w = fmaf(acc[i][3], scale, bv.w);
        *(float4*)(C + (long)(m0 + tm*4 + i) * ldc + n0 + tn * 4) = r;
    }
}

// ---------------------------------------------------------------------------
// Per (b, row): softmax over keys for 12 heads, average, exact top-256 with
// jax top_k tie-break (lower index wins), indices emitted ascending.
// Writes edge_index (as floats) and scores.
// ---------------------------------------------------------------------------
__global__ __launch_bounds__(256) void attn_post(
    const float* __restrict__ logits,  // [B][NHEADS][SS][SS]
    const int*   __restrict__ mask,    // [B][SS]
    float* __restrict__ ei,            // [2][ETOT] (float-encoded ints)
    float* __restrict__ scores)        // [ETOT]
{
    const int row = blockIdx.x;        // 0..1023
    const int b   = row >> 9;
    const int qi  = row & 511;
    const int t   = threadIdx.x;

    __shared__ float avg[SS];
    __shared__ int   flags[SS];
    __shared__ float redbuf[4];

    const bool m0 = mask[b * SS + t] != 0;
    const bool m1 = mask[b * SS + t + 256] != 0;

    float a0 = 0.f, a1 = 0.f;
    for (int h = 0; h < NHEADS; ++h) {
        const float* lr = logits + (((long)(b * NHEADS + h) * SS) + qi) * SS;
        const float l0 = m0 ? lr[t]       : -1e9f;
        const float l1 = m1 ? lr[t + 256] : -1e9f;

        float v = fmaxf(l0, l1);
        #pragma unroll
        for (int o = 32; o >= 1; o >>= 1) v = fmaxf(v, __shfl_xor(v, o));
        if ((t & 63) == 0) redbuf[t >> 6] = v;
        __syncthreads();
        const float bmax = fmaxf(fmaxf(redbuf[0], redbuf[1]), fmaxf(redbuf[2], redbuf[3]));
        __syncthreads();

        const float e0 = __expf(l0 - bmax);
        const float e1 = __expf(l1 - bmax);
        v = e0 + e1;
        #pragma unroll
        for (int o = 32; o >= 1; o >>= 1) v += __shfl_xor(v, o);
        if ((t & 63) == 0) redbuf[t >> 6] = v;
        __syncthreads();
        const float s = redbuf[0] + redbuf[1] + redbuf[2] + redbuf[3];
        __syncthreads();
        const float rs = 1.0f / s;
        a0 = fmaf(e0, rs, a0);
        a1 = fmaf(e1, rs, a1);
    }
    a0 *= (1.f / NHEADS);
    a1 *= (1.f / NHEADS);
    avg[t]       = a0;
    avg[t + 256] = a1;
    __syncthreads();

    // exact rank with (value desc, index asc) ordering
    int r0 = 0, r1 = 0;
    for (int j = 0; j < SS; ++j) {
        const float vj = avg[j];
        r0 += (vj > a0) || (vj == a0 && j < t);
        r1 += (vj > a1) || (vj == a1 && j < (t + 256));
    }
    const int sel0 = (r0 < KTOP);
    const int sel1 = (r1 < KTOP);
    flags[t]       = sel0;
    flags[t + 256] = sel1;
    __syncthreads();

    int p0 = 0, p1 = 0;
    for (int j = 0; j < SS; ++j) {
        const int f = flags[j];
        p0 += (j < t)       ? f : 0;
        p1 += (j < t + 256) ? f : 0;
    }

    const float srcv = (float)(b * SS + qi);
    const long  base = (long)row * KTOP;
    if (sel0) {
        const long e = base + p0;
        ei[e]        = srcv;
        ei[ETOT + e] = (float)(b * SS + t);
        scores[e]    = a0;
    }
    if (sel1) {
        const long e = base + p1;
        ei[e]        = srcv;
        ei[ETOT + e] = (float)(b * SS + t + 256);
        scores[e]    = a1;
    }
}

// ---------------------------------------------------------------------------
// LayerNorm over last dim (768) of node -> out[0 .. 786432)
// ---------------------------------------------------------------------------
__global__ __launch_bounds__(256) void ln_kernel(
    const float* __restrict__ node, const float* __restrict__ gamma,
    const float* __restrict__ beta, float* __restrict__ out)
{
    const int row = blockIdx.x;       // 0..1023
    const int t   = threadIdx.x;
    const float* x = node + (long)row * HH;

    const float v0 = x[t], v1 = x[t + 256], v2 = x[t + 512];
    float s  = v0 + v1 + v2;
    float sq = v0 * v0 + v1 * v1 + v2 * v2;

    __shared__ float rs_[4], rq_[4];
    #pragma unroll
    for (int o = 32; o >= 1; o >>= 1) {
        s  += __shfl_xor(s, o);
        sq += __shfl_xor(sq, o);
    }
    if ((t & 63) == 0) { rs_[t >> 6] = s; rq_[t >> 6] = sq; }
    __syncthreads();
    const float S = rs_[0] + rs_[1] + rs_[2] + rs_[3];
    const float Q = rq_[0] + rq_[1] + rq_[2] + rq_[3];
    const float mu  = S * (1.f / HH);
    const float var = Q * (1.f / HH) - mu * mu;
    const float inv = rsqrtf(var + LN_EPS);

    float* o = out + (long)row * HH;
    o[t]       = (v0 - mu) * inv * gamma[t]       + beta[t];
    o[t + 256] = (v1 - mu) * inv * gamma[t + 256] + beta[t + 256];
    o[t + 512] = (v2 - mu) * inv * gamma[t + 512] + beta[t + 512];
}

// ---------------------------------------------------------------------------
// edge_attr[e][h] = scores[e] * We[h][0] + be[h]; 805 MB streaming writes.
// 192 threads = 768/4 float4 lanes per edge row.
// ---------------------------------------------------------------------------
__global__ __launch_bounds__(192) void edge_attr_kernel(
    const float* __restrict__ scores, const float* __restrict__ We,
    const float* __restrict__ be, float* __restrict__ out)
{
    const int t = threadIdx.x;       // 0..191
    float4 w, bb;
    w.x = We[(long)(4 * t + 0) * HH];
    w.y = We[(long)(4 * t + 1) * HH];
    w.z = We[(long)(4 * t + 2) * HH];
    w.w = We[(long)(4 * t + 3) * HH];
    bb  = *(const float4*)(be + 4 * t);

    float4* o4 = (float4*)out;
    for (long e = blockIdx.x; e < ETOT; e += gridDim.x) {
        const float s = scores[e];
        float4 r;
        r.x = fmaf(s, w.x, bb.x);
        r.y = fmaf(s, w.y, bb.y);
        r.z = fmaf(s, w.z, bb.z);
        r.w = fmaf(s, w.w, bb.w);
        o4[e * (HH / 4) + t] = r;
    }
}

extern "C" void kernel_launch(void* const* d_in, const int* in_sizes, int n_in,
                              void* d_out, int out_size, void* d_ws, size_t ws_size,
                              hipStream_t stream)
{
    const float* hidden = (const float*)d_in[0];
    const int*   mask   = (const int*)  d_in[1];
    const float* Wp = (const float*)d_in[2];
    const float* bp = (const float*)d_in[3];
    const float* Wq = (const float*)d_in[4];
    const float* bq = (const float*)d_in[5];
    const float* Wk = (const float*)d_in[6];
    const float* bk = (const float*)d_in[7];
    const float* We = (const float*)d_in[8];
    const float* be = (const float*)d_in[9];
    const float* gamma = (const float*)d_in[10];
    const float* beta  = (const float*)d_in[11];

    float* out = (float*)d_out;
    float* ws  = (float*)d_ws;

    // Scratch: node + scores in d_ws (4.2 MB); q/k/logits parked in the
    // edge_attr region of d_out (written last, so they are dead by then).
    float* node   = ws;                       // 786432 floats
    float* scores = ws + 786432;              // 262144 floats
    float* q      = out + EA_OFF;             // 786432
    float* k      = out + EA_OFF + 786432;    // 786432
    float* logits = out + EA_OFF + 1572864;   // 24*512*512 = 6291456

    const dim3 blk(256);

    // node = hidden @ Wp^T + bp          [1024,768] x [768,768]^T
    gemm_at<<<dim3(12, 16, 1), blk, 0, stream>>>(hidden, Wp, bp, node,
        HH, HH, HH, HH, 0, 0, 0, 0, 0, 1.0f);
    // q = node @ Wq^T + bq ; k = node @ Wk^T + bk
    gemm_at<<<dim3(12, 16, 1), blk, 0, stream>>>(node, Wq, bq, q,
        HH, HH, HH, HH, 0, 0, 0, 0, 0, 1.0f);
    gemm_at<<<dim3(12, 16, 1), blk, 0, stream>>>(node, Wk, bk, k,
        HH, HH, HH, HH, 0, 0, 0, 0, 0, 1.0f);
    // logits[b,h] = (q_bh @ k_bh^T) / 8   [512,64] x [512,64]^T  for 24 slices
    gemm_at<<<dim3(8, 8, NB * NHEADS), blk, 0, stream>>>(q, k, nullptr, logits,
        64, HH, HH, SS,
        (long)SS * HH, 64L, (long)SS * HH, 64L, (long)SS * SS, 0.125f);
    // softmax + head-average + top-k -> edge_index + scores
    attn_post<<<dim3(NB * SS), blk, 0, stream>>>(logits, mask, out + EI_OFF, scores);
    // LayerNorm -> node_features
    ln_kernel<<<dim3(NB * SS), blk, 0, stream>>>(node, gamma, beta, out);
    // edge_attr (overwrites q/k/logits scratch; all dead by now)
    edge_attr_kernel<<<dim3(2048), dim3(192), 0, stream>>>(scores, We, be, out + EA_OFF);
}

// Round 3
// 330.991 us; speedup vs baseline: 1.2035x; 1.2035x over previous
//
#include <hip/hip_runtime.h>

#define HH 768
#define SS 512
#define NB 2
#define NHEADS 12
#define KTOP 256
#define ETOT (NB*SS*KTOP)        // 262144
#define LN_EPS 1e-5f

// Output layout (floats): node_features [786432] | edge_index [524288] | edge_attr [201326592]
#define EI_OFF 786432L
#define EA_OFF 1310720L

typedef float nfloat4 __attribute__((ext_vector_type(4)));  // NT-store-compatible

// ---------------------------------------------------------------------------
// Projection GEMM: C = A[1024,768] @ W[768,768]^T + b, hard-coded dims.
// blockIdx.z selects (W0,b0,C0) vs (W1,b1,C1) so q/k run in one dispatch.
// 64x64 tile, BK=32, 256 thr, 4x4 acc, register-prefetch of next K-tile.
// ---------------------------------------------------------------------------
__global__ __launch_bounds__(256) void gemm_proj(
    const float* __restrict__ A,
    const float* __restrict__ W0, const float* __restrict__ b0, float* __restrict__ C0,
    const float* __restrict__ W1, const float* __restrict__ b1, float* __restrict__ C1)
{
    const float* W    = blockIdx.z ? W1 : W0;
    const float* bias = blockIdx.z ? b1 : b0;
    float*       C    = blockIdx.z ? C1 : C0;

    __shared__ float As[32][68];
    __shared__ float Ws[32][68];

    const int tid = threadIdx.x;
    const int tm  = tid >> 4;          // 0..15
    const int tn  = tid & 15;          // 0..15
    const int m0  = blockIdx.y * 64;
    const int n0  = blockIdx.x * 64;
    const int srow = tid >> 3;         // 0..31
    const int sc4  = tid & 7;          // 0..7

    const float* Arow0 = A + (long)(m0 + srow)      * HH + sc4 * 4;
    const float* Arow1 = A + (long)(m0 + srow + 32) * HH + sc4 * 4;
    const float* Wrow0 = W + (long)(n0 + srow)      * HH + sc4 * 4;
    const float* Wrow1 = W + (long)(n0 + srow + 32) * HH + sc4 * 4;

    float acc[4][4] = {};
    float4 pa0 = *(const float4*)(Arow0);
    float4 pa1 = *(const float4*)(Arow1);
    float4 pw0 = *(const float4*)(Wrow0);
    float4 pw1 = *(const float4*)(Wrow1);

    for (int kt = 0; kt < HH; kt += 32) {
        __syncthreads();               // previous tile's compute done
        As[sc4*4+0][srow]    = pa0.x; As[sc4*4+1][srow]    = pa0.y;
        As[sc4*4+2][srow]    = pa0.z; As[sc4*4+3][srow]    = pa0.w;
        As[sc4*4+0][srow+32] = pa1.x; As[sc4*4+1][srow+32] = pa1.y;
        As[sc4*4+2][srow+32] = pa1.z; As[sc4*4+3][srow+32] = pa1.w;
        Ws[sc4*4+0][srow]    = pw0.x; Ws[sc4*4+1][srow]    = pw0.y;
        Ws[sc4*4+2][srow]    = pw0.z; Ws[sc4*4+3][srow]    = pw0.w;
        Ws[sc4*4+0][srow+32] = pw1.x; Ws[sc4*4+1][srow+32] = pw1.y;
        Ws[sc4*4+2][srow+32] = pw1.z; Ws[sc4*4+3][srow+32] = pw1.w;
        __syncthreads();
        if (kt + 32 < HH) {            // prefetch next tile; overlaps compute
            pa0 = *(const float4*)(Arow0 + kt + 32);
            pa1 = *(const float4*)(Arow1 + kt + 32);
            pw0 = *(const float4*)(Wrow0 + kt + 32);
            pw1 = *(const float4*)(Wrow1 + kt + 32);
        }
        #pragma unroll
        for (int k = 0; k < 32; ++k) {
            const float4 a = *(const float4*)&As[k][tm*4];
            const float4 b = *(const float4*)&Ws[k][tn*4];
            acc[0][0] = fmaf(a.x, b.x, acc[0][0]);
            acc[0][1] = fmaf(a.x, b.y, acc[0][1]);
            acc[0][2] = fmaf(a.x, b.z, acc[0][2]);
            acc[0][3] = fmaf(a.x, b.w, acc[0][3]);
            acc[1][0] = fmaf(a.y, b.x, acc[1][0]);
            acc[1][1] = fmaf(a.y, b.y, acc[1][1]);
            acc[1][2] = fmaf(a.y, b.z, acc[1][2]);
            acc[1][3] = fmaf(a.y, b.w, acc[1][3]);
            acc[2][0] = fmaf(a.z, b.x, acc[2][0]);
            acc[2][1] = fmaf(a.z, b.y, acc[2][1]);
            acc[2][2] = fmaf(a.z, b.z, acc[2][2]);
            acc[2][3] = fmaf(a.z, b.w, acc[2][3]);
            acc[3][0] = fmaf(a.w, b.x, acc[3][0]);
            acc[3][1] = fmaf(a.w, b.y, acc[3][1]);
            acc[3][2] = fmaf(a.w, b.z, acc[3][2]);
            acc[3][3] = fmaf(a.w, b.w, acc[3][3]);
        }
    }

    const float4 bv = *(const float4*)(bias + n0 + tn * 4);
    #pragma unroll
    for (int i = 0; i < 4; ++i) {
        float4 r;
        r.x = acc[i][0] + bv.x;
        r.y = acc[i][1] + bv.y;
        r.z = acc[i][2] + bv.z;
        r.w = acc[i][3] + bv.w;
        *(float4*)(C + (long)(m0 + tm*4 + i) * HH + n0 + tn * 4) = r;
    }
}

// ---------------------------------------------------------------------------
// Batched QK^T: logits[z] = (q_z [512,64] @ k_z[512,64]^T) / 8, z = b*12+h.
// ---------------------------------------------------------------------------
__global__ __launch_bounds__(256) void gemm_qk(
    const float* __restrict__ q, const float* __restrict__ k,
    float* __restrict__ logits)
{
    const int z  = blockIdx.z;
    const int bz = z / NHEADS, hz = z - bz * NHEADS;
    const float* A = q + (long)bz * SS * HH + hz * 64;
    const float* W = k + (long)bz * SS * HH + hz * 64;
    float*       C = logits + (long)z * SS * SS;

    __shared__ float As[32][68];
    __shared__ float Ws[32][68];

    const int tid = threadIdx.x;
    const int tm  = tid >> 4;
    const int tn  = tid & 15;
    const int m0  = blockIdx.y * 64;
    const int n0  = blockIdx.x * 64;
    const int srow = tid >> 3;
    const int sc4  = tid & 7;

    const float* Arow0 = A + (long)(m0 + srow)      * HH + sc4 * 4;
    const float* Arow1 = A + (long)(m0 + srow + 32) * HH + sc4 * 4;
    const float* Wrow0 = W + (long)(n0 + srow)      * HH + sc4 * 4;
    const float* Wrow1 = W + (long)(n0 + srow + 32) * HH + sc4 * 4;

    float acc[4][4] = {};
    float4 pa0 = *(const float4*)(Arow0);
    float4 pa1 = *(const float4*)(Arow1);
    float4 pw0 = *(const float4*)(Wrow0);
    float4 pw1 = *(const float4*)(Wrow1);

    for (int kt = 0; kt < 64; kt += 32) {
        __syncthreads();
        As[sc4*4+0][srow]    = pa0.x; As[sc4*4+1][srow]    = pa0.y;
        As[sc4*4+2][srow]    = pa0.z; As[sc4*4+3][srow]    = pa0.w;
        As[sc4*4+0][srow+32] = pa1.x; As[sc4*4+1][srow+32] = pa1.y;
        As[sc4*4+2][srow+32] = pa1.z; As[sc4*4+3][srow+32] = pa1.w;
        Ws[sc4*4+0][srow]    = pw0.x; Ws[sc4*4+1][srow]    = pw0.y;
        Ws[sc4*4+2][srow]    = pw0.z; Ws[sc4*4+3][srow]    = pw0.w;
        Ws[sc4*4+0][srow+32] = pw1.x; Ws[sc4*4+1][srow+32] = pw1.y;
        Ws[sc4*4+2][srow+32] = pw1.z; Ws[sc4*4+3][srow+32] = pw1.w;
        __syncthreads();
        if (kt == 0) {
            pa0 = *(const float4*)(Arow0 + 32);
            pa1 = *(const float4*)(Arow1 + 32);
            pw0 = *(const float4*)(Wrow0 + 32);
            pw1 = *(const float4*)(Wrow1 + 32);
        }
        #pragma unroll
        for (int k2 = 0; k2 < 32; ++k2) {
            const float4 a = *(const float4*)&As[k2][tm*4];
            const float4 b = *(const float4*)&Ws[k2][tn*4];
            acc[0][0] = fmaf(a.x, b.x, acc[0][0]);
            acc[0][1] = fmaf(a.x, b.y, acc[0][1]);
            acc[0][2] = fmaf(a.x, b.z, acc[0][2]);
            acc[0][3] = fmaf(a.x, b.w, acc[0][3]);
            acc[1][0] = fmaf(a.y, b.x, acc[1][0]);
            acc[1][1] = fmaf(a.y, b.y, acc[1][1]);
            acc[1][2] = fmaf(a.y, b.z, acc[1][2]);
            acc[1][3] = fmaf(a.y, b.w, acc[1][3]);
            acc[2][0] = fmaf(a.z, b.x, acc[2][0]);
            acc[2][1] = fmaf(a.z, b.y, acc[2][1]);
            acc[2][2] = fmaf(a.z, b.z, acc[2][2]);
            acc[2][3] = fmaf(a.z, b.w, acc[2][3]);
            acc[3][0] = fmaf(a.w, b.x, acc[3][0]);
            acc[3][1] = fmaf(a.w, b.y, acc[3][1]);
            acc[3][2] = fmaf(a.w, b.z, acc[3][2]);
            acc[3][3] = fmaf(a.w, b.w, acc[3][3]);
        }
    }

    #pragma unroll
    for (int i = 0; i < 4; ++i) {
        float4 r;
        r.x = acc[i][0] * 0.125f;
        r.y = acc[i][1] * 0.125f;
        r.z = acc[i][2] * 0.125f;
        r.w = acc[i][3] * 0.125f;
        *(float4*)(C + (long)(m0 + tm*4 + i) * SS + n0 + tn * 4) = r;
    }
}

// ---------------------------------------------------------------------------
// Per (b,row): softmax over keys for 12 heads (3 barriers total), average,
// exact top-256 with jax tie-break (lower index wins), indices ascending.
// ---------------------------------------------------------------------------
__global__ __launch_bounds__(256) void attn_post(
    const float* __restrict__ logits,  // [B][NHEADS][SS][SS]
    const int*   __restrict__ mask,    // [B][SS]
    float* __restrict__ ei,            // [2][ETOT] (float-encoded ints)
    float* __restrict__ scores)        // [ETOT]
{
    const int row = blockIdx.x;        // 0..1023
    const int b   = row >> 9;
    const int qi  = row & 511;
    const int t   = threadIdx.x;
    const int wid = t >> 6, lane = t & 63;

    __shared__ float avg[SS];
    __shared__ int   flags[SS];
    __shared__ float red[NHEADS][4];

    const bool m0 = mask[b * SS + t] != 0;
    const bool m1 = mask[b * SS + t + 256] != 0;

    const float* base = logits + ((long)b * NHEADS * SS + qi) * SS;
    float l0[NHEADS], l1[NHEADS];
    #pragma unroll
    for (int h = 0; h < NHEADS; ++h) {
        const float* lr = base + (long)h * SS * SS;
        l0[h] = m0 ? lr[t]       : -1e9f;
        l1[h] = m1 ? lr[t + 256] : -1e9f;
    }

    // per-head block max (wave reduce + one LDS pass)
    #pragma unroll
    for (int h = 0; h < NHEADS; ++h) {
        float v = fmaxf(l0[h], l1[h]);
        #pragma unroll
        for (int o = 32; o >= 1; o >>= 1) v = fmaxf(v, __shfl_xor(v, o));
        if (lane == 0) red[h][wid] = v;
    }
    __syncthreads();

    float e0[NHEADS], e1[NHEADS], ws_[NHEADS];
    #pragma unroll
    for (int h = 0; h < NHEADS; ++h) {
        const float bm = fmaxf(fmaxf(red[h][0], red[h][1]), fmaxf(red[h][2], red[h][3]));
        e0[h] = __expf(l0[h] - bm);
        e1[h] = __expf(l1[h] - bm);
        float v = e0[h] + e1[h];
        #pragma unroll
        for (int o = 32; o >= 1; o >>= 1) v += __shfl_xor(v, o);
        ws_[h] = v;
    }
    __syncthreads();                   // all reads of red done before overwrite
    #pragma unroll
    for (int h = 0; h < NHEADS; ++h) if (lane == 0) red[h][wid] = ws_[h];
    __syncthreads();

    float a0 = 0.f, a1 = 0.f;
    #pragma unroll
    for (int h = 0; h < NHEADS; ++h) {
        const float s  = red[h][0] + red[h][1] + red[h][2] + red[h][3];
        const float rs = 1.0f / s;
        a0 = fmaf(e0[h], rs, a0);
        a1 = fmaf(e1[h], rs, a1);
    }
    a0 *= (1.f / NHEADS);
    a1 *= (1.f / NHEADS);
    avg[t]       = a0;
    avg[t + 256] = a1;
    __syncthreads();

    // exact rank with (value desc, index asc) ordering
    int r0 = 0, r1 = 0;
    for (int j = 0; j < SS; ++j) {
        const float vj = avg[j];
        r0 += (vj > a0) || (vj == a0 && j < t);
        r1 += (vj > a1) || (vj == a1 && j < (t + 256));
    }
    const int sel0 = (r0 < KTOP);
    const int sel1 = (r1 < KTOP);
    flags[t]       = sel0;
    flags[t + 256] = sel1;
    __syncthreads();

    int p0 = 0, p1 = 0;
    for (int j = 0; j < SS; ++j) {
        const int f = flags[j];
        p0 += (j < t)       ? f : 0;
        p1 += (j < t + 256) ? f : 0;
    }

    const float srcv = (float)(b * SS + qi);
    const long  base_e = (long)row * KTOP;
    if (sel0) {
        const long e = base_e + p0;
        ei[e]        = srcv;
        ei[ETOT + e] = (float)(b * SS + t);
        scores[e]    = a0;
    }
    if (sel1) {
        const long e = base_e + p1;
        ei[e]        = srcv;
        ei[ETOT + e] = (float)(b * SS + t + 256);
        scores[e]    = a1;
    }
}

// ---------------------------------------------------------------------------
// LayerNorm over last dim (768) of node -> out[0 .. 786432)
// ---------------------------------------------------------------------------
__global__ __launch_bounds__(256) void ln_kernel(
    const float* __restrict__ node, const float* __restrict__ gamma,
    const float* __restrict__ beta, float* __restrict__ out)
{
    const int row = blockIdx.x;
    const int t   = threadIdx.x;
    const float* x = node + (long)row * HH;

    const float v0 = x[t], v1 = x[t + 256], v2 = x[t + 512];
    float s  = v0 + v1 + v2;
    float sq = v0 * v0 + v1 * v1 + v2 * v2;

    __shared__ float rs_[4], rq_[4];
    #pragma unroll
    for (int o = 32; o >= 1; o >>= 1) {
        s  += __shfl_xor(s, o);
        sq += __shfl_xor(sq, o);
    }
    if ((t & 63) == 0) { rs_[t >> 6] = s; rq_[t >> 6] = sq; }
    __syncthreads();
    const float S = rs_[0] + rs_[1] + rs_[2] + rs_[3];
    const float Q = rq_[0] + rq_[1] + rq_[2] + rq_[3];
    const float mu  = S * (1.f / HH);
    const float var = Q * (1.f / HH) - mu * mu;
    const float inv = rsqrtf(var + LN_EPS);

    float* o = out + (long)row * HH;
    o[t]       = (v0 - mu) * inv * gamma[t]       + beta[t];
    o[t + 256] = (v1 - mu) * inv * gamma[t + 256] + beta[t + 256];
    o[t + 512] = (v2 - mu) * inv * gamma[t + 512] + beta[t + 512];
}

// ---------------------------------------------------------------------------
// edge_attr[e][h] = scores[e] * We[h][0] + be[h]; 805 MB streaming writes.
// Nontemporal native-vec4 stores (pure streaming, no reuse).
// ---------------------------------------------------------------------------
__global__ __launch_bounds__(192) void edge_attr_kernel(
    const float* __restrict__ scores, const float* __restrict__ We,
    const float* __restrict__ be, float* __restrict__ out)
{
    const int t = threadIdx.x;       // 0..191
    nfloat4 w, bb;
    w.x = We[(long)(4 * t + 0) * HH];
    w.y = We[(long)(4 * t + 1) * HH];
    w.z = We[(long)(4 * t + 2) * HH];
    w.w = We[(long)(4 * t + 3) * HH];
    const float4 bv = *(const float4*)(be + 4 * t);
    bb.x = bv.x; bb.y = bv.y; bb.z = bv.z; bb.w = bv.w;

    nfloat4* o4 = (nfloat4*)out;
    for (long e = blockIdx.x; e < ETOT; e += gridDim.x) {
        const float s = scores[e];
        nfloat4 r;
        r.x = fmaf(s, w.x, bb.x);
        r.y = fmaf(s, w.y, bb.y);
        r.z = fmaf(s, w.z, bb.z);
        r.w = fmaf(s, w.w, bb.w);
        __builtin_nontemporal_store(r, &o4[e * (HH / 4) + t]);
    }
}

extern "C" void kernel_launch(void* const* d_in, const int* in_sizes, int n_in,
                              void* d_out, int out_size, void* d_ws, size_t ws_size,
                              hipStream_t stream)
{
    const float* hidden = (const float*)d_in[0];
    const int*   mask   = (const int*)  d_in[1];
    const float* Wp = (const float*)d_in[2];
    const float* bp = (const float*)d_in[3];
    const float* Wq = (const float*)d_in[4];
    const float* bq = (const float*)d_in[5];
    const float* Wk = (const float*)d_in[6];
    const float* bk = (const float*)d_in[7];
    const float* We = (const float*)d_in[8];
    const float* be = (const float*)d_in[9];
    const float* gamma = (const float*)d_in[10];
    const float* beta  = (const float*)d_in[11];

    float* out = (float*)d_out;
    float* ws  = (float*)d_ws;

    // Scratch: node + scores in d_ws (4.2 MB); q/k/logits parked in the
    // edge_attr region of d_out (written last, so they are dead by then).
    float* node   = ws;                       // 786432 floats
    float* scores = ws + 786432;              // 262144 floats
    float* q      = out + EA_OFF;             // 786432
    float* k      = out + EA_OFF + 786432;    // 786432
    float* logits = out + EA_OFF + 1572864;   // 24*512*512 = 6291456

    const dim3 blk(256);

    // node = hidden @ Wp^T + bp
    gemm_proj<<<dim3(12, 16, 1), blk, 0, stream>>>(hidden, Wp, bp, node,
                                                   Wp, bp, node);
    // q = node @ Wq^T + bq ; k = node @ Wk^T + bk  (one dispatch, z=2)
    gemm_proj<<<dim3(12, 16, 2), blk, 0, stream>>>(node, Wq, bq, q,
                                                   Wk, bk, k);
    // logits[b,h] = (q_bh @ k_bh^T) / 8
    gemm_qk<<<dim3(8, 8, NB * NHEADS), blk, 0, stream>>>(q, k, logits);
    // softmax + head-average + top-k -> edge_index + scores
    attn_post<<<dim3(NB * SS), blk, 0, stream>>>(logits, mask, out + EI_OFF, scores);
    // LayerNorm -> node_features
    ln_kernel<<<dim3(NB * SS), blk, 0, stream>>>(node, gamma, beta, out);
    // edge_attr (overwrites q/k/logits scratch; all dead by now)
    edge_attr_kernel<<<dim3(2048), dim3(192), 0, stream>>>(scores, We, be, out + EA_OFF);
}